// Round 14
// baseline (203.286 us; speedup 1.0000x reference)
//
#include <hip/hip_runtime.h>
#include <cstdint>
#include <cstddef>

// ---------------------------------------------------------------------------
// GCN 3-layer forward, CSR-gather formulation:
//   out[d] = dinv[d] * ( sum_{s in N(d)} T'[s] + T'[d] ) + b,
//   with T'[r] = bf16( dinv[r] * (X[r] @ W) ).
// Round 13: gather + next-layer matmul FUSED (k_gmm): 4 waves gather 16 rows
// into fp32 LDS (stride-68 pad -> 2-way conflicts only), one sync, then each
// wave does one 16x16 n-tile of the next matmul (3-term compensated MFMA).
// Deletes the A round-trip (51 MB) and 2 dispatches. A is fp32 in LDS ->
// one fewer bf16 rounding than round 12.
// Chain: mm_f(x)->T1, gmm<64>(T1->T2), gmm<32>(T2->T3=T1buf), gather32->out.
// ---------------------------------------------------------------------------

#define CH 4096      // edges per S3 block
#define BSHIFT 8     // 256 dsts per bucket
#define BSIZE 256
#define CAP 4096     // padded capacity per bucket (mean 2558, sigma 51)
// assumes n <= 131072 (src fits 17 bits) and NB <= 512; n = 100000 -> NB=391.

typedef short bf16x8 __attribute__((ext_vector_type(8)));
typedef float f32x4 __attribute__((ext_vector_type(4)));

__device__ __forceinline__ int eidx_at(const void* p, long long i, int is64) {
  if (is64) return (int)((const long long*)p)[i];
  return ((const int*)p)[i];
}

// int64 node indices are all < 1e5; int32 data read as u64 has a random index
// in the high word -> huge values. Call from wave 0 only.
__device__ __forceinline__ int detect64(const void* eidx) {
  const unsigned long long* p = (const unsigned long long*)eidx;
  int lane = threadIdx.x & 63;
  int bad = 0;
#pragma unroll
  for (int i = 0; i < 4; ++i) bad |= (p[lane + 64 * i] > 1000000000ULL) ? 1 : 0;
  return __any(bad) ? 0 : 1;
}

__device__ __forceinline__ unsigned short f2bf(float f) {
  unsigned u = __float_as_uint(f);
  unsigned r = (u + 0x7FFFu + ((u >> 16) & 1u)) >> 16;   // RNE
  return (unsigned short)r;
}
__device__ __forceinline__ float bf2f(unsigned short h) {
  return __uint_as_float((unsigned)h << 16);
}

// S3: single edge-list read. Stage (src,dst) in LDS + LDS histogram; reserve
// each bucket's slice with ONE global atomicAdd per (block,bucket) into
// cursor (zeroed by tiny memset); scatter packed words into the bucket's
// fixed window [b*CAP, b*CAP + cursor[b]).
__global__ __launch_bounds__(256) void k_s3(const void* eidx,
                                            int* __restrict__ cursor,
                                            unsigned int* __restrict__ packed,
                                            int E, int NB) {
  __shared__ int ss[CH];     // src
  __shared__ int sd[CH];     // dst
  __shared__ int h[512];
  __shared__ int cur[512];
  __shared__ int s_is64;
  int t = threadIdx.x, blk = blockIdx.x;
  for (int i = t; i < NB; i += 256) h[i] = 0;
  if (t < 64) { int r = detect64(eidx); if (t == 0) s_is64 = r; }
  __syncthreads();
  int is64 = s_is64;
  int lo = blk * CH, hi = min(lo + CH, E);
  int cnt = hi - lo;
  for (int i = t; i < cnt; i += 256) {
    int s = eidx_at(eidx, lo + i, is64);
    int d = eidx_at(eidx, (long long)E + lo + i, is64);
    ss[i] = s;
    sd[i] = d;
    atomicAdd(&h[d >> BSHIFT], 1);
  }
  __syncthreads();
  for (int i = t; i < NB; i += 256)
    cur[i] = h[i] ? (i * CAP + atomicAdd(&cursor[i], h[i])) : 0;
  __syncthreads();
  for (int i = t; i < cnt; i += 256) {
    int d = sd[i];
    int pos = atomicAdd(&cur[d >> BSHIFT], 1);  // LDS atomic
    packed[pos] = ((unsigned)(d & (BSIZE - 1)) << 17) | (unsigned)ss[i];
  }
}

// S4: one block per bucket, one node per thread. LDS hist over the bucket's
// window -> rowbeg/rowcnt/dinv (coalesced), then scatter csr_src in-window.
__global__ __launch_bounds__(256) void k_s4(const unsigned int* __restrict__ packed,
                                            const int* __restrict__ cursor,
                                            int* __restrict__ rowbeg,
                                            int* __restrict__ rowcnt,
                                            float* __restrict__ dinv,
                                            int* __restrict__ csr_src, int n) {
  int b = blockIdx.x, t = threadIdx.x;
  int lo = b * CAP;
  int hi = lo + cursor[b];
  __shared__ int h[256];
  __shared__ int ps[256];
  __shared__ int cur[256];
  h[t] = 0;
  __syncthreads();
  for (int i = lo + t; i < hi; i += 256)
    atomicAdd(&h[packed[i] >> 17], 1);
  __syncthreads();
  int a0 = h[t];
  ps[t] = a0;
  __syncthreads();
  for (int off = 1; off < 256; off <<= 1) {
    int x = (t >= off) ? ps[t - off] : 0;
    __syncthreads();
    ps[t] += x;
    __syncthreads();
  }
  int e0 = lo + ps[t] - a0;   // exclusive, within this bucket's window
  cur[t] = e0;
  int node = b * BSIZE + t;
  if (node < n) {
    rowbeg[node] = e0;
    rowcnt[node] = a0;
    dinv[node] = rsqrtf((float)(a0 + 1));
  }
  __syncthreads();
  for (int i = lo + t; i < hi; i += 256) {
    unsigned p = packed[i];
    int pos = atomicAdd(&cur[p >> 17], 1);  // LDS atomic
    csr_src[pos] = (int)(p & 0x1FFFFu);
  }
}

// MFMA matmul, fp32 input (layer 1): T' = bf16(dinv * (X @ W)).
// Compensated split X=Xh+Xl, W=Wh+Wl; acc = XhWh + XhWl + XlWh.
// Layouts (m89/m97): A/B lane l holds 8 contiguous k at k=(l>>4)*8+i,
// row/col = l&15; D: col=l&15, row=(l>>4)*4+reg.
template <int COUT>
__global__ __launch_bounds__(256) void k_mm_f(const float* __restrict__ X,
                                              const float* __restrict__ W,
                                              const float* __restrict__ dinv,
                                              unsigned short* __restrict__ T, int n) {
  const int NT = COUT / 16;
  int lane = threadIdx.x & 63;
  int wid = blockIdx.x * (blockDim.x >> 6) + (threadIdx.x >> 6);
  int rowb = wid * 16;
  if (rowb >= n) return;
  int lr = lane & 15;
  int lk = lane >> 4;

  bf16x8 wh[2 * NT], wl[2 * NT];
#pragma unroll
  for (int kk = 0; kk < 2; ++kk) {
#pragma unroll
    for (int nt = 0; nt < NT; ++nt) {
#pragma unroll
      for (int i = 0; i < 8; ++i) {
        int k = kk * 32 + lk * 8 + i;
        float w = W[k * COUT + nt * 16 + lr];
        unsigned short h = f2bf(w);
        wh[kk * NT + nt][i] = (short)h;
        wl[kk * NT + nt][i] = (short)f2bf(w - bf2f(h));
      }
    }
  }

  const float* ar = X + (size_t)(rowb + lr) * 64;
  bf16x8 ah[2], al[2];
#pragma unroll
  for (int kk = 0; kk < 2; ++kk) {
    float4 v0 = *(const float4*)(ar + kk * 32 + lk * 8);
    float4 v1 = *(const float4*)(ar + kk * 32 + lk * 8 + 4);
    float vv[8] = {v0.x, v0.y, v0.z, v0.w, v1.x, v1.y, v1.z, v1.w};
#pragma unroll
    for (int i = 0; i < 8; ++i) {
      unsigned short h = f2bf(vv[i]);
      ah[kk][i] = (short)h;
      al[kk][i] = (short)f2bf(vv[i] - bf2f(h));
    }
  }

  f32x4 acc[NT];
#pragma unroll
  for (int nt = 0; nt < NT; ++nt) {
    f32x4 a = {0.f, 0.f, 0.f, 0.f};
#pragma unroll
    for (int kk = 0; kk < 2; ++kk) {
      a = __builtin_amdgcn_mfma_f32_16x16x32_bf16(ah[kk], wh[kk * NT + nt], a, 0, 0, 0);
      a = __builtin_amdgcn_mfma_f32_16x16x32_bf16(ah[kk], wl[kk * NT + nt], a, 0, 0, 0);
      a = __builtin_amdgcn_mfma_f32_16x16x32_bf16(al[kk], wh[kk * NT + nt], a, 0, 0, 0);
    }
    acc[nt] = a;
  }

#pragma unroll
  for (int j = 0; j < 4; ++j) {
    int row = rowb + lk * 4 + j;
    float dr = dinv[row];
#pragma unroll
    for (int nt = 0; nt < NT; ++nt)
      T[(size_t)row * COUT + nt * 16 + lr] = f2bf(acc[nt][j] * dr);
  }
}

// FUSED gather + next-layer matmul. Block = 4 waves = 16 rows.
// Phase 1 (all waves): wave w gathers rows rowb+4w..rowb+4w+3 (64 lanes =
// 64 features, 8/4/1-batched bf16 loads, fp32 acc), applies dinv/bias/relu,
// parks fp32 row in LDS As[16][68] (pad 68 -> 2-way bank conflict = free).
// Phase 2 (wave nt < COUT/16): one 16x16 n-tile of T_out = bf16(dinv*(A@W)),
// 3-term compensated MFMA split (A fp32 exactness preserved).
template <int COUT>
__global__ __launch_bounds__(256) void k_gmm(const unsigned short* __restrict__ T_in,
                                             const int* __restrict__ rowbeg,
                                             const int* __restrict__ rowcnt,
                                             const int* __restrict__ csr_src,
                                             const float* __restrict__ dinv,
                                             const float* __restrict__ bias,
                                             const float* __restrict__ Wn,
                                             unsigned short* __restrict__ T_out,
                                             int n) {
  const int CIN = 64;
  const int NT = COUT / 16;
  __shared__ float As[16][68];
  __shared__ float sdi[16];
  int tid = threadIdx.x;
  int wave = tid >> 6, lane = tid & 63;
  int rowb = blockIdx.x * 16;

  // ---- phase 1: gather 4 rows per wave ----
#pragma unroll
  for (int rr = 0; rr < 4; ++rr) {
    int lrow = wave * 4 + rr;
    int row = rowb + lrow;
    if (row < n) {
      int beg = rowbeg[row];
      int end = beg + rowcnt[row];
      float dr = dinv[row];
      float a0 = 0.f, a1 = 0.f, a2 = 0.f, a3 = 0.f;
      int j = beg;
      for (; j + 8 <= end; j += 8) {
        int s0 = csr_src[j + 0], s1 = csr_src[j + 1], s2 = csr_src[j + 2], s3 = csr_src[j + 3];
        int s4 = csr_src[j + 4], s5 = csr_src[j + 5], s6 = csr_src[j + 6], s7 = csr_src[j + 7];
        float t0 = bf2f(T_in[(size_t)s0 * CIN + lane]);
        float t1 = bf2f(T_in[(size_t)s1 * CIN + lane]);
        float t2 = bf2f(T_in[(size_t)s2 * CIN + lane]);
        float t3 = bf2f(T_in[(size_t)s3 * CIN + lane]);
        float t4 = bf2f(T_in[(size_t)s4 * CIN + lane]);
        float t5 = bf2f(T_in[(size_t)s5 * CIN + lane]);
        float t6 = bf2f(T_in[(size_t)s6 * CIN + lane]);
        float t7 = bf2f(T_in[(size_t)s7 * CIN + lane]);
        a0 += t0; a1 += t1; a2 += t2; a3 += t3;
        a0 += t4; a1 += t5; a2 += t6; a3 += t7;
      }
      if (j + 4 <= end) {
        int s0 = csr_src[j + 0], s1 = csr_src[j + 1], s2 = csr_src[j + 2], s3 = csr_src[j + 3];
        float t0 = bf2f(T_in[(size_t)s0 * CIN + lane]);
        float t1 = bf2f(T_in[(size_t)s1 * CIN + lane]);
        float t2 = bf2f(T_in[(size_t)s2 * CIN + lane]);
        float t3 = bf2f(T_in[(size_t)s3 * CIN + lane]);
        a0 += t0; a1 += t1; a2 += t2; a3 += t3;
        j += 4;
      }
      for (; j < end; ++j) {
        int s = csr_src[j];
        a0 += bf2f(T_in[(size_t)s * CIN + lane]);
      }
      float acc = (a0 + a1) + (a2 + a3);
      float v = fmaf(dr, acc + bf2f(T_in[(size_t)row * CIN + lane]), bias[lane]);
      v = fmaxf(v, 0.f);          // relu (both fused layers have it)
      As[lrow][lane] = v;
      if (lane == 0) sdi[lrow] = dr;
    } else {
      As[lrow][lane] = 0.f;
      if (lane == 0) sdi[lrow] = 0.f;
    }
  }
  __syncthreads();

  // ---- phase 2: one n-tile per wave ----
  if (wave >= NT) return;
  int nt = wave;
  int lr = lane & 15, lk = lane >> 4;

  bf16x8 wh[2], wl[2];
#pragma unroll
  for (int kk = 0; kk < 2; ++kk) {
#pragma unroll
    for (int i = 0; i < 8; ++i) {
      int k = kk * 32 + lk * 8 + i;
      float w = Wn[k * COUT + nt * 16 + lr];
      unsigned short h = f2bf(w);
      wh[kk][i] = (short)h;
      wl[kk][i] = (short)f2bf(w - bf2f(h));
    }
  }

  bf16x8 ah[2], al[2];
#pragma unroll
  for (int kk = 0; kk < 2; ++kk) {
#pragma unroll
    for (int i = 0; i < 8; ++i) {
      float v = As[lr][kk * 32 + lk * 8 + i];
      unsigned short h = f2bf(v);
      ah[kk][i] = (short)h;
      al[kk][i] = (short)f2bf(v - bf2f(h));
    }
  }

  f32x4 a = {0.f, 0.f, 0.f, 0.f};
#pragma unroll
  for (int kk = 0; kk < 2; ++kk) {
    a = __builtin_amdgcn_mfma_f32_16x16x32_bf16(ah[kk], wh[kk], a, 0, 0, 0);
    a = __builtin_amdgcn_mfma_f32_16x16x32_bf16(ah[kk], wl[kk], a, 0, 0, 0);
    a = __builtin_amdgcn_mfma_f32_16x16x32_bf16(al[kk], wh[kk], a, 0, 0, 0);
  }

#pragma unroll
  for (int j = 0; j < 4; ++j) {
    int row = rowb + lk * 4 + j;
    if (row < n)
      T_out[(size_t)row * COUT + nt * 16 + lr] = f2bf(a[j] * sdi[lk * 4 + j]);
  }
}

// Final gather, COUT=32: TWO rows per wave (one per 32-lane half), fp32 out.
__global__ __launch_bounds__(256) void k_gather32(const unsigned short* __restrict__ T,
                                                  const int* __restrict__ rowbeg,
                                                  const int* __restrict__ rowcnt,
                                                  const int* __restrict__ csr_src,
                                                  const float* __restrict__ dinv,
                                                  const float* __restrict__ b,
                                                  float* __restrict__ outp, int n) {
  const int COUT = 32;
  int wave = blockIdx.x * (blockDim.x >> 6) + (threadIdx.x >> 6);
  int half = (threadIdx.x >> 5) & 1;
  int l = threadIdx.x & 31;
  int row = wave * 2 + half;
  if (row >= n) return;
  int beg = rowbeg[row];
  int end = beg + rowcnt[row];
  float dr = dinv[row];
  float a0 = 0.f, a1 = 0.f, a2 = 0.f, a3 = 0.f;
  int j = beg;
  for (; j + 8 <= end; j += 8) {
    int s0 = csr_src[j + 0], s1 = csr_src[j + 1], s2 = csr_src[j + 2], s3 = csr_src[j + 3];
    int s4 = csr_src[j + 4], s5 = csr_src[j + 5], s6 = csr_src[j + 6], s7 = csr_src[j + 7];
    float t0 = bf2f(T[(size_t)s0 * COUT + l]);
    float t1 = bf2f(T[(size_t)s1 * COUT + l]);
    float t2 = bf2f(T[(size_t)s2 * COUT + l]);
    float t3 = bf2f(T[(size_t)s3 * COUT + l]);
    float t4 = bf2f(T[(size_t)s4 * COUT + l]);
    float t5 = bf2f(T[(size_t)s5 * COUT + l]);
    float t6 = bf2f(T[(size_t)s6 * COUT + l]);
    float t7 = bf2f(T[(size_t)s7 * COUT + l]);
    a0 += t0; a1 += t1; a2 += t2; a3 += t3;
    a0 += t4; a1 += t5; a2 += t6; a3 += t7;
  }
  if (j + 4 <= end) {
    int s0 = csr_src[j + 0], s1 = csr_src[j + 1], s2 = csr_src[j + 2], s3 = csr_src[j + 3];
    float t0 = bf2f(T[(size_t)s0 * COUT + l]);
    float t1 = bf2f(T[(size_t)s1 * COUT + l]);
    float t2 = bf2f(T[(size_t)s2 * COUT + l]);
    float t3 = bf2f(T[(size_t)s3 * COUT + l]);
    a0 += t0; a1 += t1; a2 += t2; a3 += t3;
    j += 4;
  }
  for (; j < end; ++j) {
    int s = csr_src[j];
    a0 += bf2f(T[(size_t)s * COUT + l]);
  }
  float acc = (a0 + a1) + (a2 + a3);
  float v = fmaf(dr, acc + bf2f(T[(size_t)row * COUT + l]), b[l]);
  outp[(size_t)row * COUT + l] = v;
}

extern "C" void kernel_launch(void* const* d_in, const int* in_sizes, int n_in,
                              void* d_out, int out_size, void* d_ws, size_t ws_size,
                              hipStream_t stream) {
  const float* x  = (const float*)d_in[0];
  const void*  ei = d_in[1];
  const float* W1 = (const float*)d_in[2];
  const float* b1 = (const float*)d_in[3];
  const float* W2 = (const float*)d_in[4];
  const float* b2 = (const float*)d_in[5];
  const float* W3 = (const float*)d_in[6];
  const float* b3 = (const float*)d_in[7];
  float* out = (float*)d_out;

  const int n = in_sizes[0] / 64;   // 100000 (multiple of 16)
  const int E = in_sizes[1] / 2;    // 1000000

  const int NB   = (n + BSIZE - 1) / BSIZE;  // 391 buckets
  const int NBLK = (E + CH - 1) / CH;        // 245 edge blocks

  char* ws = (char*)d_ws;
  size_t off = 0;
  auto carve = [&](size_t bytes) -> void* {
    void* p = ws + off;
    off = (off + bytes + 255) & ~(size_t)255;
    return p;
  };
  float*          dinv    = (float*)carve(sizeof(float) * n);
  int*            rowbeg  = (int*)carve(sizeof(int) * n);
  int*            rowcnt  = (int*)carve(sizeof(int) * n);
  int*            cursor  = (int*)carve(sizeof(int) * 512);
  unsigned*       packed  = (unsigned*)carve(sizeof(unsigned) * (size_t)NB * CAP);
  int*            csr_src = (int*)carve(sizeof(int) * (size_t)NB * CAP);
  unsigned short* T1      = (unsigned short*)carve(sizeof(unsigned short) * (size_t)n * 64);
  unsigned short* T2      = (unsigned short*)carve(sizeof(unsigned short) * (size_t)n * 64);
  unsigned short* T3      = T1;   // T1 dead once gmm<64> has produced T2

  const int B = 256;
  const int gW32 = (n + 7) / 8;                 // 2 rows/wave, 4 waves/block
  const int gMM  = ((n + 15) / 16 + 3) / 4;     // mm_f: 16 rows/wave, 4 waves/blk
  const int gGMM = (n + 15) / 16;               // gmm: 16 rows/block

  // ---- CSR build: 1.5KB memset + 2 dispatches (edge list read ONCE) ----
  hipMemsetAsync(cursor, 0, sizeof(int) * NB, stream);
  k_s3<<<NBLK, B, 0, stream>>>(ei, cursor, packed, E, NB);
  k_s4<<<NB, B, 0, stream>>>(packed, cursor, rowbeg, rowcnt, dinv, csr_src, n);

  // ---- layer 1 matmul: x (fp32) -> T1 (bf16) ----
  k_mm_f<64><<<gMM, B, 0, stream>>>(x, W1, dinv, T1, n);

  // ---- gather1 + matmul2 fused: T1 -> T2 ----
  k_gmm<64><<<gGMM, B, 0, stream>>>(T1, rowbeg, rowcnt, csr_src, dinv, b1, W2, T2, n);

  // ---- gather2 + matmul3 fused: T2 -> T3 ----
  k_gmm<32><<<gGMM, B, 0, stream>>>(T2, rowbeg, rowcnt, csr_src, dinv, b2, W3, T3, n);

  // ---- final gather: T3 -> out (fp32) ----
  k_gather32<<<gW32, B, 0, stream>>>(T3, rowbeg, rowcnt, csr_src, dinv, b3, out, n);
}

// Round 15
// 177.487 us; speedup vs baseline: 1.1454x; 1.1454x over previous
//
#include <hip/hip_runtime.h>
#include <cstdint>
#include <cstddef>

// ---------------------------------------------------------------------------
// GCN 3-layer forward, CSR-gather formulation:
//   out[d] = dinv[d] * ( sum_{s in N(d)} T'[s] + T'[d] ) + b,
//   with T'[r] = bf16( dinv[r] * (X[r] @ W) ).
// Round 14: REVERT to round-12 structure (measured best, 178 us). Round-13
// fusion (gather+mm in one kernel) regressed 178->203: it serialized 4 rows
// per wave (100k->25k waves, occ 66->52%) on a latency-bound phase — the
// 51 MB of A-traffic saved was dwarfed by lost TLP. Lesson: don't trade
// parallelism for locality on a service-rate-bound gather.
// Build: fixed-capacity bucket sort (CAP=4096/bucket), edge list read ONCE,
// all fine-grained atomics in LDS; 2 dispatches + 1.5KB memset.
// ---------------------------------------------------------------------------

#define CH 4096      // edges per S3 block
#define BSHIFT 8     // 256 dsts per bucket
#define BSIZE 256
#define CAP 4096     // padded capacity per bucket (mean 2558, sigma 51)
// assumes n <= 131072 (src fits 17 bits) and NB <= 512; n = 100000 -> NB=391.

typedef short bf16x8 __attribute__((ext_vector_type(8)));
typedef float f32x4 __attribute__((ext_vector_type(4)));

__device__ __forceinline__ int eidx_at(const void* p, long long i, int is64) {
  if (is64) return (int)((const long long*)p)[i];
  return ((const int*)p)[i];
}

// int64 node indices are all < 1e5; int32 data read as u64 has a random index
// in the high word -> huge values. Call from wave 0 only.
__device__ __forceinline__ int detect64(const void* eidx) {
  const unsigned long long* p = (const unsigned long long*)eidx;
  int lane = threadIdx.x & 63;
  int bad = 0;
#pragma unroll
  for (int i = 0; i < 4; ++i) bad |= (p[lane + 64 * i] > 1000000000ULL) ? 1 : 0;
  return __any(bad) ? 0 : 1;
}

__device__ __forceinline__ unsigned short f2bf(float f) {
  unsigned u = __float_as_uint(f);
  unsigned r = (u + 0x7FFFu + ((u >> 16) & 1u)) >> 16;   // RNE
  return (unsigned short)r;
}
__device__ __forceinline__ float bf2f(unsigned short h) {
  return __uint_as_float((unsigned)h << 16);
}

// S3: single edge-list read. Stage (src,dst) in LDS + LDS histogram; reserve
// each bucket's slice with ONE global atomicAdd per (block,bucket) into
// cursor (zeroed by tiny memset); scatter packed words into the bucket's
// fixed window [b*CAP, b*CAP + cursor[b]).
__global__ __launch_bounds__(256) void k_s3(const void* eidx,
                                            int* __restrict__ cursor,
                                            unsigned int* __restrict__ packed,
                                            int E, int NB) {
  __shared__ int ss[CH];     // src
  __shared__ int sd[CH];     // dst
  __shared__ int h[512];
  __shared__ int cur[512];
  __shared__ int s_is64;
  int t = threadIdx.x, blk = blockIdx.x;
  for (int i = t; i < NB; i += 256) h[i] = 0;
  if (t < 64) { int r = detect64(eidx); if (t == 0) s_is64 = r; }
  __syncthreads();
  int is64 = s_is64;
  int lo = blk * CH, hi = min(lo + CH, E);
  int cnt = hi - lo;
  for (int i = t; i < cnt; i += 256) {
    int s = eidx_at(eidx, lo + i, is64);
    int d = eidx_at(eidx, (long long)E + lo + i, is64);
    ss[i] = s;
    sd[i] = d;
    atomicAdd(&h[d >> BSHIFT], 1);
  }
  __syncthreads();
  for (int i = t; i < NB; i += 256)
    cur[i] = h[i] ? (i * CAP + atomicAdd(&cursor[i], h[i])) : 0;
  __syncthreads();
  for (int i = t; i < cnt; i += 256) {
    int d = sd[i];
    int pos = atomicAdd(&cur[d >> BSHIFT], 1);  // LDS atomic
    packed[pos] = ((unsigned)(d & (BSIZE - 1)) << 17) | (unsigned)ss[i];
  }
}

// S4: one block per bucket, one node per thread. LDS hist over the bucket's
// window -> rowbeg/rowcnt/dinv (coalesced), then scatter csr_src in-window.
__global__ __launch_bounds__(256) void k_s4(const unsigned int* __restrict__ packed,
                                            const int* __restrict__ cursor,
                                            int* __restrict__ rowbeg,
                                            int* __restrict__ rowcnt,
                                            float* __restrict__ dinv,
                                            int* __restrict__ csr_src, int n) {
  int b = blockIdx.x, t = threadIdx.x;
  int lo = b * CAP;
  int hi = lo + cursor[b];
  __shared__ int h[256];
  __shared__ int ps[256];
  __shared__ int cur[256];
  h[t] = 0;
  __syncthreads();
  for (int i = lo + t; i < hi; i += 256)
    atomicAdd(&h[packed[i] >> 17], 1);
  __syncthreads();
  int a0 = h[t];
  ps[t] = a0;
  __syncthreads();
  for (int off = 1; off < 256; off <<= 1) {
    int x = (t >= off) ? ps[t - off] : 0;
    __syncthreads();
    ps[t] += x;
    __syncthreads();
  }
  int e0 = lo + ps[t] - a0;   // exclusive, within this bucket's window
  cur[t] = e0;
  int node = b * BSIZE + t;
  if (node < n) {
    rowbeg[node] = e0;
    rowcnt[node] = a0;
    dinv[node] = rsqrtf((float)(a0 + 1));
  }
  __syncthreads();
  for (int i = lo + t; i < hi; i += 256) {
    unsigned p = packed[i];
    int pos = atomicAdd(&cur[p >> 17], 1);  // LDS atomic
    csr_src[pos] = (int)(p & 0x1FFFFu);
  }
}

// MFMA matmul, fp32 input (layer 1): T' = bf16(dinv * (X @ W)).
// Compensated split X=Xh+Xl, W=Wh+Wl; acc = XhWh + XhWl + XlWh.
// Layouts (m89/m97): A/B lane l holds 8 contiguous k at k=(l>>4)*8+i,
// row/col = l&15; D: col=l&15, row=(l>>4)*4+reg.
template <int COUT>
__global__ __launch_bounds__(256) void k_mm_f(const float* __restrict__ X,
                                              const float* __restrict__ W,
                                              const float* __restrict__ dinv,
                                              unsigned short* __restrict__ T, int n) {
  const int NT = COUT / 16;
  int lane = threadIdx.x & 63;
  int wid = blockIdx.x * (blockDim.x >> 6) + (threadIdx.x >> 6);
  int rowb = wid * 16;
  if (rowb >= n) return;
  int lr = lane & 15;
  int lk = lane >> 4;

  bf16x8 wh[2 * NT], wl[2 * NT];
#pragma unroll
  for (int kk = 0; kk < 2; ++kk) {
#pragma unroll
    for (int nt = 0; nt < NT; ++nt) {
#pragma unroll
      for (int i = 0; i < 8; ++i) {
        int k = kk * 32 + lk * 8 + i;
        float w = W[k * COUT + nt * 16 + lr];
        unsigned short h = f2bf(w);
        wh[kk * NT + nt][i] = (short)h;
        wl[kk * NT + nt][i] = (short)f2bf(w - bf2f(h));
      }
    }
  }

  const float* ar = X + (size_t)(rowb + lr) * 64;
  bf16x8 ah[2], al[2];
#pragma unroll
  for (int kk = 0; kk < 2; ++kk) {
    float4 v0 = *(const float4*)(ar + kk * 32 + lk * 8);
    float4 v1 = *(const float4*)(ar + kk * 32 + lk * 8 + 4);
    float vv[8] = {v0.x, v0.y, v0.z, v0.w, v1.x, v1.y, v1.z, v1.w};
#pragma unroll
    for (int i = 0; i < 8; ++i) {
      unsigned short h = f2bf(vv[i]);
      ah[kk][i] = (short)h;
      al[kk][i] = (short)f2bf(vv[i] - bf2f(h));
    }
  }

  f32x4 acc[NT];
#pragma unroll
  for (int nt = 0; nt < NT; ++nt) {
    f32x4 a = {0.f, 0.f, 0.f, 0.f};
#pragma unroll
    for (int kk = 0; kk < 2; ++kk) {
      a = __builtin_amdgcn_mfma_f32_16x16x32_bf16(ah[kk], wh[kk * NT + nt], a, 0, 0, 0);
      a = __builtin_amdgcn_mfma_f32_16x16x32_bf16(ah[kk], wl[kk * NT + nt], a, 0, 0, 0);
      a = __builtin_amdgcn_mfma_f32_16x16x32_bf16(al[kk], wh[kk * NT + nt], a, 0, 0, 0);
    }
    acc[nt] = a;
  }

#pragma unroll
  for (int j = 0; j < 4; ++j) {
    int row = rowb + lk * 4 + j;
    float dr = dinv[row];
#pragma unroll
    for (int nt = 0; nt < NT; ++nt)
      T[(size_t)row * COUT + nt * 16 + lr] = f2bf(acc[nt][j] * dr);
  }
}

// MFMA matmul, bf16 input (layers 2/3): input exact -> 2-term split
// acc = A*Wh + A*Wl. A fragments loaded directly (bf16x8, 16B).
template <int COUT>
__global__ __launch_bounds__(256) void k_mm_b(const unsigned short* __restrict__ Xb,
                                              const float* __restrict__ W,
                                              const float* __restrict__ dinv,
                                              unsigned short* __restrict__ T, int n) {
  const int NT = COUT / 16;
  int lane = threadIdx.x & 63;
  int wid = blockIdx.x * (blockDim.x >> 6) + (threadIdx.x >> 6);
  int rowb = wid * 16;
  if (rowb >= n) return;
  int lr = lane & 15;
  int lk = lane >> 4;

  bf16x8 wh[2 * NT], wl[2 * NT];
#pragma unroll
  for (int kk = 0; kk < 2; ++kk) {
#pragma unroll
    for (int nt = 0; nt < NT; ++nt) {
#pragma unroll
      for (int i = 0; i < 8; ++i) {
        int k = kk * 32 + lk * 8 + i;
        float w = W[k * COUT + nt * 16 + lr];
        unsigned short h = f2bf(w);
        wh[kk * NT + nt][i] = (short)h;
        wl[kk * NT + nt][i] = (short)f2bf(w - bf2f(h));
      }
    }
  }

  const unsigned short* ar = Xb + (size_t)(rowb + lr) * 64;
  bf16x8 av[2];
#pragma unroll
  for (int kk = 0; kk < 2; ++kk)
    av[kk] = *(const bf16x8*)(ar + kk * 32 + lk * 8);

  f32x4 acc[NT];
#pragma unroll
  for (int nt = 0; nt < NT; ++nt) {
    f32x4 a = {0.f, 0.f, 0.f, 0.f};
#pragma unroll
    for (int kk = 0; kk < 2; ++kk) {
      a = __builtin_amdgcn_mfma_f32_16x16x32_bf16(av[kk], wh[kk * NT + nt], a, 0, 0, 0);
      a = __builtin_amdgcn_mfma_f32_16x16x32_bf16(av[kk], wl[kk * NT + nt], a, 0, 0, 0);
    }
    acc[nt] = a;
  }

#pragma unroll
  for (int j = 0; j < 4; ++j) {
    int row = rowb + lk * 4 + j;
    float dr = dinv[row];
#pragma unroll
    for (int nt = 0; nt < NT; ++nt)
      T[(size_t)row * COUT + nt * 16 + lr] = f2bf(acc[nt][j] * dr);
  }
}

// Gather, COUT=64: one wave per dst row (64 lanes = 64 features).
// acc = sum T'[src[j]] (batched 8/4/1, independent bf16 loads, fp32 acc),
// then v = dinv*(acc + T'[row]) + b. OUTBF: bf16 vs fp32 store.
template <bool RELU, bool OUTBF>
__global__ __launch_bounds__(256) void k_gather64(const unsigned short* __restrict__ T,
                                                  const int* __restrict__ rowbeg,
                                                  const int* __restrict__ rowcnt,
                                                  const int* __restrict__ csr_src,
                                                  const float* __restrict__ dinv,
                                                  const float* __restrict__ b,
                                                  void* __restrict__ outp, int n) {
  const int COUT = 64;
  int wave = blockIdx.x * (blockDim.x >> 6) + (threadIdx.x >> 6);
  int lane = threadIdx.x & 63;
  int row = __builtin_amdgcn_readfirstlane(wave);
  if (row >= n) return;
  int beg = rowbeg[row];
  int end = beg + rowcnt[row];
  float dr = dinv[row];
  float a0 = 0.f, a1 = 0.f, a2 = 0.f, a3 = 0.f;
  int j = beg;
  for (; j + 8 <= end; j += 8) {
    int s0 = csr_src[j + 0], s1 = csr_src[j + 1], s2 = csr_src[j + 2], s3 = csr_src[j + 3];
    int s4 = csr_src[j + 4], s5 = csr_src[j + 5], s6 = csr_src[j + 6], s7 = csr_src[j + 7];
    float t0 = bf2f(T[(size_t)s0 * COUT + lane]);
    float t1 = bf2f(T[(size_t)s1 * COUT + lane]);
    float t2 = bf2f(T[(size_t)s2 * COUT + lane]);
    float t3 = bf2f(T[(size_t)s3 * COUT + lane]);
    float t4 = bf2f(T[(size_t)s4 * COUT + lane]);
    float t5 = bf2f(T[(size_t)s5 * COUT + lane]);
    float t6 = bf2f(T[(size_t)s6 * COUT + lane]);
    float t7 = bf2f(T[(size_t)s7 * COUT + lane]);
    a0 += t0; a1 += t1; a2 += t2; a3 += t3;
    a0 += t4; a1 += t5; a2 += t6; a3 += t7;
  }
  if (j + 4 <= end) {
    int s0 = csr_src[j + 0], s1 = csr_src[j + 1], s2 = csr_src[j + 2], s3 = csr_src[j + 3];
    float t0 = bf2f(T[(size_t)s0 * COUT + lane]);
    float t1 = bf2f(T[(size_t)s1 * COUT + lane]);
    float t2 = bf2f(T[(size_t)s2 * COUT + lane]);
    float t3 = bf2f(T[(size_t)s3 * COUT + lane]);
    a0 += t0; a1 += t1; a2 += t2; a3 += t3;
    j += 4;
  }
  for (; j < end; ++j) {
    int s = csr_src[j];
    a0 += bf2f(T[(size_t)s * COUT + lane]);
  }
  float acc = (a0 + a1) + (a2 + a3);
  float v = fmaf(dr, acc + bf2f(T[(size_t)row * COUT + lane]), b[lane]);
  if (RELU) v = fmaxf(v, 0.f);
  if (OUTBF)
    ((unsigned short*)outp)[(size_t)row * COUT + lane] = f2bf(v);
  else
    ((float*)outp)[(size_t)row * COUT + lane] = v;
}

// Gather, COUT=32: TWO rows per wave (one per 32-lane half), all lanes active.
template <bool RELU, bool OUTBF>
__global__ __launch_bounds__(256) void k_gather32(const unsigned short* __restrict__ T,
                                                  const int* __restrict__ rowbeg,
                                                  const int* __restrict__ rowcnt,
                                                  const int* __restrict__ csr_src,
                                                  const float* __restrict__ dinv,
                                                  const float* __restrict__ b,
                                                  void* __restrict__ outp, int n) {
  const int COUT = 32;
  int wave = blockIdx.x * (blockDim.x >> 6) + (threadIdx.x >> 6);
  int half = (threadIdx.x >> 5) & 1;
  int l = threadIdx.x & 31;
  int row = wave * 2 + half;
  if (row >= n) return;
  int beg = rowbeg[row];
  int end = beg + rowcnt[row];
  float dr = dinv[row];
  float a0 = 0.f, a1 = 0.f, a2 = 0.f, a3 = 0.f;
  int j = beg;
  for (; j + 8 <= end; j += 8) {
    int s0 = csr_src[j + 0], s1 = csr_src[j + 1], s2 = csr_src[j + 2], s3 = csr_src[j + 3];
    int s4 = csr_src[j + 4], s5 = csr_src[j + 5], s6 = csr_src[j + 6], s7 = csr_src[j + 7];
    float t0 = bf2f(T[(size_t)s0 * COUT + l]);
    float t1 = bf2f(T[(size_t)s1 * COUT + l]);
    float t2 = bf2f(T[(size_t)s2 * COUT + l]);
    float t3 = bf2f(T[(size_t)s3 * COUT + l]);
    float t4 = bf2f(T[(size_t)s4 * COUT + l]);
    float t5 = bf2f(T[(size_t)s5 * COUT + l]);
    float t6 = bf2f(T[(size_t)s6 * COUT + l]);
    float t7 = bf2f(T[(size_t)s7 * COUT + l]);
    a0 += t0; a1 += t1; a2 += t2; a3 += t3;
    a0 += t4; a1 += t5; a2 += t6; a3 += t7;
  }
  if (j + 4 <= end) {
    int s0 = csr_src[j + 0], s1 = csr_src[j + 1], s2 = csr_src[j + 2], s3 = csr_src[j + 3];
    float t0 = bf2f(T[(size_t)s0 * COUT + l]);
    float t1 = bf2f(T[(size_t)s1 * COUT + l]);
    float t2 = bf2f(T[(size_t)s2 * COUT + l]);
    float t3 = bf2f(T[(size_t)s3 * COUT + l]);
    a0 += t0; a1 += t1; a2 += t2; a3 += t3;
    j += 4;
  }
  for (; j < end; ++j) {
    int s = csr_src[j];
    a0 += bf2f(T[(size_t)s * COUT + l]);
  }
  float acc = (a0 + a1) + (a2 + a3);
  float v = fmaf(dr, acc + bf2f(T[(size_t)row * COUT + l]), b[l]);
  if (RELU) v = fmaxf(v, 0.f);
  if (OUTBF)
    ((unsigned short*)outp)[(size_t)row * COUT + l] = f2bf(v);
  else
    ((float*)outp)[(size_t)row * COUT + l] = v;
}

extern "C" void kernel_launch(void* const* d_in, const int* in_sizes, int n_in,
                              void* d_out, int out_size, void* d_ws, size_t ws_size,
                              hipStream_t stream) {
  const float* x  = (const float*)d_in[0];
  const void*  ei = d_in[1];
  const float* W1 = (const float*)d_in[2];
  const float* b1 = (const float*)d_in[3];
  const float* W2 = (const float*)d_in[4];
  const float* b2 = (const float*)d_in[5];
  const float* W3 = (const float*)d_in[6];
  const float* b3 = (const float*)d_in[7];
  float* out = (float*)d_out;

  const int n = in_sizes[0] / 64;   // 100000 (multiple of 16)
  const int E = in_sizes[1] / 2;    // 1000000

  const int NB   = (n + BSIZE - 1) / BSIZE;  // 391 buckets
  const int NBLK = (E + CH - 1) / CH;        // 245 edge blocks

  char* ws = (char*)d_ws;
  size_t off = 0;
  auto carve = [&](size_t bytes) -> void* {
    void* p = ws + off;
    off = (off + bytes + 255) & ~(size_t)255;
    return p;
  };
  float*          dinv    = (float*)carve(sizeof(float) * n);
  int*            rowbeg  = (int*)carve(sizeof(int) * n);
  int*            rowcnt  = (int*)carve(sizeof(int) * n);
  int*            cursor  = (int*)carve(sizeof(int) * 512);
  unsigned*       packed  = (unsigned*)carve(sizeof(unsigned) * (size_t)NB * CAP);
  int*            csr_src = (int*)carve(sizeof(int) * (size_t)NB * CAP);
  unsigned short* T       = (unsigned short*)carve(sizeof(unsigned short) * (size_t)n * 64);
  unsigned short* A       = (unsigned short*)carve(sizeof(unsigned short) * (size_t)n * 64);

  const int B = 256;
  const int gW64 = (n + 3) / 4;                 // 1 row/wave, 4 waves/block
  const int gW32 = (n + 7) / 8;                 // 2 rows/wave, 4 waves/block
  const int gMM  = ((n + 15) / 16 + 3) / 4;     // 16 rows/wave, 4 waves/block

  // ---- CSR build: 1.5KB memset + 2 dispatches (edge list read ONCE) ----
  hipMemsetAsync(cursor, 0, sizeof(int) * NB, stream);
  k_s3<<<NBLK, B, 0, stream>>>(ei, cursor, packed, E, NB);
  k_s4<<<NB, B, 0, stream>>>(packed, cursor, rowbeg, rowcnt, dinv, csr_src, n);

  // ---- layer 1: x (fp32) -> A (bf16) ----
  k_mm_f<64><<<gMM, B, 0, stream>>>(x, W1, dinv, T, n);
  k_gather64<true, true><<<gW64, B, 0, stream>>>(T, rowbeg, rowcnt, csr_src, dinv, b1, A, n);

  // ---- layer 2: A (bf16) -> A (bf16) ----
  k_mm_b<64><<<gMM, B, 0, stream>>>(A, W2, dinv, T, n);
  k_gather64<true, true><<<gW64, B, 0, stream>>>(T, rowbeg, rowcnt, csr_src, dinv, b2, A, n);

  // ---- layer 3: A (bf16) -> out (fp32) ----
  k_mm_b<32><<<gMM, B, 0, stream>>>(A, W3, dinv, T, n);
  k_gather32<false, false><<<gW32, B, 0, stream>>>(T, rowbeg, rowcnt, csr_src, dinv, b3, out, n);
}